// Round 12
// baseline (370.708 us; speedup 1.0000x reference)
//
#include <hip/hip_runtime.h>
#include <math.h>

#define B 4
#define LK 256
#define LQ 128
#define D 32
#define ET 128
#define H 4
#define NH 128
#define DK 32
#define TWO_D 64
#define G3 384
#define QTILE 4

// workspace offsets (floats)
#define OFF_KP 0
#define SZ_KP (B*LK*ET)            // 131072
#define OFF_QP (OFF_KP + SZ_KP)
#define SZ_QP (LQ*ET)              // 16384
#define OFF_OUT (OFF_QP + SZ_QP)
#define SZ_OUT (B*LQ*NH)           // 65536
#define OFF_GI (OFF_OUT + SZ_OUT)
#define SZ_GI (2*LQ*B*G3)          // 393216
#define OFF_H (OFF_GI + SZ_GI)
#define SZ_H (2*LQ*B*NH)           // 131072

typedef float f2 __attribute__((ext_vector_type(2)));

#if defined(__has_builtin)
#if __has_builtin(__builtin_elementwise_fma)
#define VFMA(a,b,c) __builtin_elementwise_fma((a),(b),(c))
#else
#define VFMA(a,b,c) ((a)*(b)+(c))
#endif
#else
#define VFMA(a,b,c) ((a)*(b)+(c))
#endif

__device__ __forceinline__ float fsig(float x) {
    // 1/(1+e^-x); v_exp + v_rcp, ~1e-7 rel err
    return __builtin_amdgcn_rcpf(1.f + __expf(-x));
}
__device__ __forceinline__ float ftanh2(float x) {
    // tanh(x) = 2*sigmoid(2x) - 1
    return fmaf(2.f, fsig(x + x), -1.f);
}

// ---------------- time embedding + Q/K projections ----------------
// blocks 0..B*LK-1: key rows; blocks B*LK..B*LK+LQ-1: query rows. 128 threads.
__global__ __launch_bounds__(128) void k_emb_proj(
        const float* __restrict__ ts, const float* __restrict__ qref,
        const float* __restrict__ wlin, const float* __restrict__ blin,
        const float* __restrict__ wper, const float* __restrict__ bper,
        const float* __restrict__ wq, const float* __restrict__ bq,
        const float* __restrict__ wk, const float* __restrict__ bk,
        float* __restrict__ ws) {
    __shared__ float e[ET];
    int blk = blockIdx.x;
    int j = threadIdx.x;
    float t;
    const float *wmat, *bvec;
    float* outp;
    if (blk < B*LK) {
        t = ts[blk];
        wmat = wk; bvec = bk; outp = ws + OFF_KP + blk*ET;
    } else {
        int q = blk - B*LK;
        t = qref[q];
        wmat = wq; bvec = bq; outp = ws + OFF_QP + q*ET;
    }
    e[j] = (j == 0) ? fmaf(t, wlin[0], blin[0])
                    : __sinf(fmaf(t, wper[j-1], bper[j-1]));
    __syncthreads();
    const f2* w2 = (const f2*)(wmat + j*ET);
    const f2* e2 = (const f2*)e;
    f2 a0 = {0.f,0.f}, a1 = {0.f,0.f}, a2 = {0.f,0.f}, a3 = {0.f,0.f};
    #pragma unroll
    for (int c = 0; c < ET/2; c += 4) {
        a0 = VFMA(w2[c+0], e2[c+0], a0);
        a1 = VFMA(w2[c+1], e2[c+1], a1);
        a2 = VFMA(w2[c+2], e2[c+2], a2);
        a3 = VFMA(w2[c+3], e2[c+3], a3);
    }
    f2 aa = (a0 + a1) + (a2 + a3);
    outp[j] = bvec[j] + aa.x + aa.y;
}

// ---------------- attention ----------------
// grid = B*32 blocks, 256 threads; each block: 1 batch, QTILE=4 queries.
__global__ __launch_bounds__(256) void k_attn(
        const float* __restrict__ x, const float* __restrict__ wo,
        const float* __restrict__ bo, float* __restrict__ ws) {
    int b  = blockIdx.x >> 5;
    int q0 = (blockIdx.x & 31) * QTILE;
    int tid = threadIdx.x;
    __shared__ float xt[LK*TWO_D];   // 64 KB: x[b] staged once
    __shared__ float qv[ET];
    __shared__ float earr[H*LK];
    __shared__ float P[4*H*TWO_D];
    __shared__ float Nl[H*TWO_D];
    __shared__ float attf[H*TWO_D];

    const float* ksrc = ws + OFF_KP + b*LK*ET;
    const float4* xsrc4 = (const float4*)(x + b*LK*TWO_D);
    float4* xt4 = (float4*)xt;
    for (int i = tid; i < LK*TWO_D/4; i += 256) xt4[i] = xsrc4[i];

    int h = tid >> 6, lane = tid & 63;
    int fg = lane & 15, kc = lane >> 4;

    for (int qi = 0; qi < QTILE; ++qi) {
        int q = q0 + qi;
        if (tid < ET) qv[tid] = ws[OFF_QP + q*ET + tid];
        __syncthreads();

        // scores + per-head (wave) max + exp
        float s[4];
        float mx = -1e30f;
        #pragma unroll
        for (int i = 0; i < 4; ++i) {
            int k = lane + 64*i;
            const f2* kp2 = (const f2*)(ksrc + k*ET + h*DK);
            const f2* q2  = (const f2*)(qv + h*DK);
            f2 a0 = {0.f,0.f}, a1 = {0.f,0.f};
            #pragma unroll
            for (int c = 0; c < DK/2; c += 2) {
                a0 = VFMA(kp2[c+0], q2[c+0], a0);
                a1 = VFMA(kp2[c+1], q2[c+1], a1);
            }
            f2 aa = a0 + a1;
            s[i] = (aa.x + aa.y) * 0.17677669529663687f;   // 1/sqrt(32)
            mx = fmaxf(mx, s[i]);
        }
        #pragma unroll
        for (int off = 32; off > 0; off >>= 1)
            mx = fmaxf(mx, __shfl_xor(mx, off, 64));
        #pragma unroll
        for (int i = 0; i < 4; ++i)
            earr[h*LK + lane + 64*i] = __expf(s[i] - mx);
        __syncthreads();

        // N[h][f] = sum_k e[h][k] * x[b][k][f]  (kc = 4 k-chunks)
        f2 accl = {0.f,0.f}, acch = {0.f,0.f};
        const float* ep = earr + h*LK + kc*64;
        #pragma unroll 4
        for (int k = 0; k < 64; ++k) {
            float e = ep[k];
            f2 ee = {e, e};
            const f2* xv = (const f2*)(xt + (kc*64 + k)*TWO_D + fg*4);
            accl = VFMA(ee, xv[0], accl);
            acch = VFMA(ee, xv[1], acch);
        }
        {
            float4 acc4;
            acc4.x = accl.x; acc4.y = accl.y; acc4.z = acch.x; acc4.w = acch.y;
            *(float4*)(P + kc*(H*TWO_D) + h*TWO_D + fg*4) = acc4;
        }
        __syncthreads();
        {
            int hh2 = tid >> 6, f = tid & 63;
            float n = P[0*(H*TWO_D) + hh2*TWO_D + f] + P[1*(H*TWO_D) + hh2*TWO_D + f]
                    + P[2*(H*TWO_D) + hh2*TWO_D + f] + P[3*(H*TWO_D) + hh2*TWO_D + f];
            Nl[hh2*TWO_D + f] = n;
        }
        __syncthreads();
        {
            int hh2 = tid >> 6, f = tid & 63;
            attf[hh2*TWO_D + f] = Nl[hh2*TWO_D + f] / Nl[hh2*TWO_D + 32 + (f & 31)];
        }
        __syncthreads();

        if (tid < NH) {
            const f2* wrow = (const f2*)(wo + tid*(H*TWO_D));
            const f2* a2 = (const f2*)attf;
            f2 c0 = {0.f,0.f}, c1 = {0.f,0.f}, c2 = {0.f,0.f}, c3 = {0.f,0.f};
            #pragma unroll
            for (int jj = 0; jj < (H*TWO_D)/2; jj += 4) {
                c0 = VFMA(wrow[jj+0], a2[jj+0], c0);
                c1 = VFMA(wrow[jj+1], a2[jj+1], c1);
                c2 = VFMA(wrow[jj+2], a2[jj+2], c2);
                c3 = VFMA(wrow[jj+3], a2[jj+3], c3);
            }
            f2 cc = (c0 + c1) + (c2 + c3);
            ws[OFF_OUT + (b*LQ + q)*NH + tid] = bo[tid] + cc.x + cc.y;
        }
        __syncthreads();
    }
}

// ---------------- gi = xs @ wih.T + bih for both directions ----------------
__global__ __launch_bounds__(384) void k_gi(
        const float* __restrict__ wih_f, const float* __restrict__ bih_f,
        const float* __restrict__ wih_b, const float* __restrict__ bih_b,
        float* __restrict__ ws) {
    int dir = blockIdx.x >> 7;
    int t = blockIdx.x & 127;
    int r = threadIdx.x;
    __shared__ float xr[B*NH];
    for (int i = r; i < B*NH; i += 384) {
        int bb = i >> 7, j = i & 127;
        xr[i] = ws[OFF_OUT + (bb*LQ + t)*NH + j];
    }
    __syncthreads();
    const float* wih = dir ? wih_b : wih_f;
    const float* bih = dir ? bih_b : bih_f;
    const f2* w2 = (const f2*)(wih + r*NH);
    const f2* x0 = (const f2*)(xr + 0*NH);
    const f2* x1 = (const f2*)(xr + 1*NH);
    const f2* x2 = (const f2*)(xr + 2*NH);
    const f2* x3 = (const f2*)(xr + 3*NH);
    f2 a0 = {0.f,0.f}, a1 = {0.f,0.f}, a2 = {0.f,0.f}, a3 = {0.f,0.f};
    #pragma unroll
    for (int c = 0; c < NH/2; ++c) {
        f2 w = w2[c];
        a0 = VFMA(w, x0[c], a0);
        a1 = VFMA(w, x1[c], a1);
        a2 = VFMA(w, x2[c], a2);
        a3 = VFMA(w, x3[c], a3);
    }
    float bb0 = bih[r];
    float* gid = ws + OFF_GI + dir*(LQ*B*G3) + t*(B*G3);
    gid[0*G3 + r] = bb0 + a0.x + a0.y;
    gid[1*G3 + r] = bb0 + a1.x + a1.y;
    gid[2*G3 + r] = bb0 + a2.x + a2.y;
    gid[3*G3 + r] = bb0 + a3.x + a3.y;
}

// ---------------- sequential GRU ----------------
// grid = 8 blocks (dir,b), 128 threads. Thread j owns gate rows {j, 128+j, 256+j}
// with all 3 whh rows in registers (384 VGPRs); gate math thread-local, no gh
// exchange; double-buffered h in LDS -> ONE barrier per step; gi prefetched.
__global__ __launch_bounds__(128, 1) void k_gru(
        const float* __restrict__ whh_f, const float* __restrict__ bhh_f,
        const float* __restrict__ whh_b, const float* __restrict__ bhh_b,
        float* __restrict__ ws) {
    int dir = blockIdx.x >> 2;
    int b = blockIdx.x & 3;
    int j = threadIdx.x;
    __shared__ float4 hbuf[2][NH/4];
    const float* whh = dir ? whh_b : whh_f;
    const float* bhh = dir ? bhh_b : bhh_f;

    f2 wr[NH/2], wz[NH/2], wn[NH/2];
    #pragma unroll
    for (int c = 0; c < NH/2; ++c) wr[c] = ((const f2*)(whh + (j       )*NH))[c];
    #pragma unroll
    for (int c = 0; c < NH/2; ++c) wz[c] = ((const f2*)(whh + (NH   + j)*NH))[c];
    #pragma unroll
    for (int c = 0; c < NH/2; ++c) wn[c] = ((const f2*)(whh + (2*NH + j)*NH))[c];
    float bhr = bhh[j], bhz = bhh[NH + j], bhn = bhh[2*NH + j];

    ((float*)hbuf[0])[j] = 0.f;
    float hprev = 0.f;

    const float* gbase = ws + OFF_GI + dir*(LQ*B*G3) + b*G3;
    float* hbase = ws + OFF_H + dir*(LQ*B*NH) + b*NH;

    // gi for step 0
    int tt0 = dir ? (LQ - 1) : 0;
    const float* gp0 = gbase + tt0*(B*G3);
    float gir = gp0[j], giz = gp0[NH + j], gin = gp0[2*NH + j];
    __syncthreads();

    for (int t = 0; t < LQ; ++t) {
        int tt = dir ? (LQ - 1 - t) : t;
        // prefetch next step's gi (independent of recurrence)
        float ngr = 0.f, ngz = 0.f, ngn = 0.f;
        if (t + 1 < LQ) {
            int tn = dir ? (LQ - 2 - t) : (t + 1);
            const float* gp = gbase + tn*(B*G3);
            ngr = gp[j]; ngz = gp[NH + j]; ngn = gp[2*NH + j];
        }
        // 3-row dot against broadcast h (ds_read_b128)
        const float4* h4 = hbuf[t & 1];
        f2 ar0 = {0.f,0.f}, ar1 = {0.f,0.f};
        f2 az0 = {0.f,0.f}, az1 = {0.f,0.f};
        f2 an0 = {0.f,0.f}, an1 = {0.f,0.f};
        #pragma unroll
        for (int c = 0; c < NH/4; ++c) {
            float4 hv = h4[c];
            f2 hlo = {hv.x, hv.y}, hhi = {hv.z, hv.w};
            ar0 = VFMA(wr[2*c+0], hlo, ar0); ar1 = VFMA(wr[2*c+1], hhi, ar1);
            az0 = VFMA(wz[2*c+0], hlo, az0); az1 = VFMA(wz[2*c+1], hhi, az1);
            an0 = VFMA(wn[2*c+0], hlo, an0); an1 = VFMA(wn[2*c+1], hhi, an1);
        }
        f2 arr = ar0 + ar1; f2 azz = az0 + az1; f2 ann = an0 + an1;
        float ghr = bhr + arr.x + arr.y;
        float ghz = bhz + azz.x + azz.y;
        float ghn = bhn + ann.x + ann.y;

        float rg = fsig(gir + ghr);
        float zg = fsig(giz + ghz);
        float ng = ftanh2(gin + rg * ghn);
        float hn = (1.f - zg) * ng + zg * hprev;

        ((float*)hbuf[(t + 1) & 1])[j] = hn;
        hbase[tt*(B*NH) + j] = hn;
        hprev = hn;
        gir = ngr; giz = ngz; gin = ngn;
        __syncthreads();
    }
}

// ---------------- final MLP ----------------
__global__ __launch_bounds__(64) void k_mlp(
        const float* __restrict__ w1, const float* __restrict__ b1,
        const float* __restrict__ w2, const float* __restrict__ b2,
        const float* __restrict__ ws, float* __restrict__ out) {
    int b = blockIdx.x >> 7;
    int q = blockIdx.x & 127;
    int tid = threadIdx.x;
    __shared__ float hh[2*NH];
    __shared__ float hid[64];
    for (int i = tid; i < 2*NH; i += 64) {
        int dir = i >> 7, j = i & 127;
        hh[i] = ws[OFF_H + dir*(LQ*B*NH) + (q*B + b)*NH + j];
    }
    __syncthreads();
    if (tid < 50) {
        const f2* w2v = (const f2*)(w1 + tid*(2*NH));
        const f2* h2v = (const f2*)hh;
        f2 a0 = {0.f,0.f}, a1 = {0.f,0.f}, a2 = {0.f,0.f}, a3 = {0.f,0.f};
        #pragma unroll
        for (int c = 0; c < (2*NH)/2; c += 4) {
            a0 = VFMA(w2v[c+0], h2v[c+0], a0);
            a1 = VFMA(w2v[c+1], h2v[c+1], a1);
            a2 = VFMA(w2v[c+2], h2v[c+2], a2);
            a3 = VFMA(w2v[c+3], h2v[c+3], a3);
        }
        f2 aa = (a0 + a1) + (a2 + a3);
        hid[tid] = fmaxf(b1[tid] + aa.x + aa.y, 0.f);
    }
    __syncthreads();
    if (tid < 40) {
        float acc = b2[tid];
        const float* wr = w2 + tid*50;
        #pragma unroll
        for (int i = 0; i < 50; ++i) acc = fmaf(wr[i], hid[i], acc);
        out[(b*LQ + q)*40 + tid] = acc;
    }
}

extern "C" void kernel_launch(void* const* d_in, const int* in_sizes, int n_in,
                              void* d_out, int out_size, void* d_ws, size_t ws_size,
                              hipStream_t stream) {
    const float* x     = (const float*)d_in[0];
    const float* ts    = (const float*)d_in[1];
    const float* qref  = (const float*)d_in[2];
    const float* wlin  = (const float*)d_in[3];
    const float* blin  = (const float*)d_in[4];
    const float* wper  = (const float*)d_in[5];
    const float* bper  = (const float*)d_in[6];
    const float* wq    = (const float*)d_in[7];
    const float* bq    = (const float*)d_in[8];
    const float* wk    = (const float*)d_in[9];
    const float* bk    = (const float*)d_in[10];
    const float* wo    = (const float*)d_in[11];
    const float* bo    = (const float*)d_in[12];
    const float* wih_f = (const float*)d_in[13];
    const float* whh_f = (const float*)d_in[14];
    const float* bih_f = (const float*)d_in[15];
    const float* bhh_f = (const float*)d_in[16];
    const float* wih_b = (const float*)d_in[17];
    const float* whh_b = (const float*)d_in[18];
    const float* bih_b = (const float*)d_in[19];
    const float* bhh_b = (const float*)d_in[20];
    const float* w1    = (const float*)d_in[21];
    const float* b1    = (const float*)d_in[22];
    const float* w2    = (const float*)d_in[23];
    const float* b2    = (const float*)d_in[24];
    float* ws = (float*)d_ws;
    float* out = (float*)d_out;

    k_emb_proj<<<B*LK + LQ, 128, 0, stream>>>(ts, qref, wlin, blin, wper, bper,
                                              wq, bq, wk, bk, ws);
    k_attn<<<B*(LQ/QTILE), 256, 0, stream>>>(x, wo, bo, ws);
    k_gi<<<2*LQ, 384, 0, stream>>>(wih_f, bih_f, wih_b, bih_b, ws);
    k_gru<<<8, 128, 0, stream>>>(whh_f, bhh_f, whh_b, bhh_b, ws);
    k_mlp<<<B*LQ, 64, 0, stream>>>(w1, b1, w2, b2, ws, out);
}

// Round 15
// 251.479 us; speedup vs baseline: 1.4741x; 1.4741x over previous
//
#include <hip/hip_runtime.h>
#include <math.h>

#define B 4
#define LK 256
#define LQ 128
#define D 32
#define ET 128
#define H 4
#define NH 128
#define DK 32
#define TWO_D 64
#define G3 384
#define QTILE 2

// workspace offsets (floats)
#define OFF_KP 0
#define SZ_KP (B*LK*ET)            // 131072
#define OFF_QP (OFF_KP + SZ_KP)
#define SZ_QP (LQ*ET)              // 16384
#define OFF_OUT (OFF_QP + SZ_QP)
#define SZ_OUT (B*LQ*NH)           // 65536
#define OFF_GI (OFF_OUT + SZ_OUT)
#define SZ_GI (2*LQ*B*G3)          // 393216
#define OFF_H (OFF_GI + SZ_GI)
#define SZ_H (2*LQ*B*NH)           // 131072

typedef float f2 __attribute__((ext_vector_type(2)));

#if defined(__has_builtin)
#if __has_builtin(__builtin_elementwise_fma)
#define VFMA(a,b,c) __builtin_elementwise_fma((a),(b),(c))
#else
#define VFMA(a,b,c) ((a)*(b)+(c))
#endif
#else
#define VFMA(a,b,c) ((a)*(b)+(c))
#endif

__device__ __forceinline__ float fsig(float x) {
    return __builtin_amdgcn_rcpf(1.f + __expf(-x));
}
__device__ __forceinline__ float ftanh2(float x) {
    return fmaf(2.f, fsig(x + x), -1.f);
}

// ---------------- time embedding + Q/K projections ----------------
__global__ __launch_bounds__(128) void k_emb_proj(
        const float* __restrict__ ts, const float* __restrict__ qref,
        const float* __restrict__ wlin, const float* __restrict__ blin,
        const float* __restrict__ wper, const float* __restrict__ bper,
        const float* __restrict__ wq, const float* __restrict__ bq,
        const float* __restrict__ wk, const float* __restrict__ bk,
        float* __restrict__ ws) {
    __shared__ float e[ET];
    int blk = blockIdx.x;
    int j = threadIdx.x;
    float t;
    const float *wmat, *bvec;
    float* outp;
    if (blk < B*LK) {
        t = ts[blk];
        wmat = wk; bvec = bk; outp = ws + OFF_KP + blk*ET;
    } else {
        int q = blk - B*LK;
        t = qref[q];
        wmat = wq; bvec = bq; outp = ws + OFF_QP + q*ET;
    }
    e[j] = (j == 0) ? fmaf(t, wlin[0], blin[0])
                    : __sinf(fmaf(t, wper[j-1], bper[j-1]));
    __syncthreads();
    const f2* w2 = (const f2*)(wmat + j*ET);
    const f2* e2 = (const f2*)e;
    f2 a0 = {0.f,0.f}, a1 = {0.f,0.f}, a2 = {0.f,0.f}, a3 = {0.f,0.f};
    #pragma unroll
    for (int c = 0; c < ET/2; c += 4) {
        a0 = VFMA(w2[c+0], e2[c+0], a0);
        a1 = VFMA(w2[c+1], e2[c+1], a1);
        a2 = VFMA(w2[c+2], e2[c+2], a2);
        a3 = VFMA(w2[c+3], e2[c+3], a3);
    }
    f2 aa = (a0 + a1) + (a2 + a3);
    outp[j] = bvec[j] + aa.x + aa.y;
}

// ---------------- attention ----------------
// grid = B*64 blocks (QTILE=2 queries each), 256 threads -> full chip + 2x stage amortization.
__global__ __launch_bounds__(256) void k_attn(
        const float* __restrict__ x, const float* __restrict__ wo,
        const float* __restrict__ bo, float* __restrict__ ws) {
    int b  = blockIdx.x >> 6;
    int q0 = (blockIdx.x & 63) * QTILE;
    int tid = threadIdx.x;
    __shared__ float xt[LK*TWO_D];   // 64 KB: x[b] staged once per block
    __shared__ float qv[ET];
    __shared__ float earr[H*LK];
    __shared__ float P[4*H*TWO_D];
    __shared__ float Nl[H*TWO_D];
    __shared__ float attf[H*TWO_D];

    const float* ksrc = ws + OFF_KP + b*LK*ET;
    const float4* xsrc4 = (const float4*)(x + b*LK*TWO_D);
    float4* xt4 = (float4*)xt;
    for (int i = tid; i < LK*TWO_D/4; i += 256) xt4[i] = xsrc4[i];

    int h = tid >> 6, lane = tid & 63;
    int fg = lane & 15, kc = lane >> 4;

    for (int qi = 0; qi < QTILE; ++qi) {
        int q = q0 + qi;
        if (tid < ET) qv[tid] = ws[OFF_QP + q*ET + tid];
        __syncthreads();

        float s[4];
        float mx = -1e30f;
        #pragma unroll
        for (int i = 0; i < 4; ++i) {
            int k = lane + 64*i;
            const f2* kp2 = (const f2*)(ksrc + k*ET + h*DK);
            const f2* q2  = (const f2*)(qv + h*DK);
            f2 a0 = {0.f,0.f}, a1 = {0.f,0.f};
            #pragma unroll
            for (int c = 0; c < DK/2; c += 2) {
                a0 = VFMA(kp2[c+0], q2[c+0], a0);
                a1 = VFMA(kp2[c+1], q2[c+1], a1);
            }
            f2 aa = a0 + a1;
            s[i] = (aa.x + aa.y) * 0.17677669529663687f;   // 1/sqrt(32)
            mx = fmaxf(mx, s[i]);
        }
        #pragma unroll
        for (int off = 32; off > 0; off >>= 1)
            mx = fmaxf(mx, __shfl_xor(mx, off, 64));
        #pragma unroll
        for (int i = 0; i < 4; ++i)
            earr[h*LK + lane + 64*i] = __expf(s[i] - mx);
        __syncthreads();

        f2 accl = {0.f,0.f}, acch = {0.f,0.f};
        const float* ep = earr + h*LK + kc*64;
        #pragma unroll 4
        for (int k = 0; k < 64; ++k) {
            float e = ep[k];
            f2 ee = {e, e};
            const f2* xv = (const f2*)(xt + (kc*64 + k)*TWO_D + fg*4);
            accl = VFMA(ee, xv[0], accl);
            acch = VFMA(ee, xv[1], acch);
        }
        {
            float4 acc4;
            acc4.x = accl.x; acc4.y = accl.y; acc4.z = acch.x; acc4.w = acch.y;
            *(float4*)(P + kc*(H*TWO_D) + h*TWO_D + fg*4) = acc4;
        }
        __syncthreads();
        {
            int hh2 = tid >> 6, f = tid & 63;
            float n = P[0*(H*TWO_D) + hh2*TWO_D + f] + P[1*(H*TWO_D) + hh2*TWO_D + f]
                    + P[2*(H*TWO_D) + hh2*TWO_D + f] + P[3*(H*TWO_D) + hh2*TWO_D + f];
            Nl[hh2*TWO_D + f] = n;
        }
        __syncthreads();
        {
            int hh2 = tid >> 6, f = tid & 63;
            attf[hh2*TWO_D + f] = Nl[hh2*TWO_D + f] / Nl[hh2*TWO_D + 32 + (f & 31)];
        }
        __syncthreads();

        if (tid < NH) {
            const f2* wrow = (const f2*)(wo + tid*(H*TWO_D));
            const f2* a2 = (const f2*)attf;
            f2 c0 = {0.f,0.f}, c1 = {0.f,0.f}, c2 = {0.f,0.f}, c3 = {0.f,0.f};
            #pragma unroll
            for (int jj = 0; jj < (H*TWO_D)/2; jj += 4) {
                c0 = VFMA(wrow[jj+0], a2[jj+0], c0);
                c1 = VFMA(wrow[jj+1], a2[jj+1], c1);
                c2 = VFMA(wrow[jj+2], a2[jj+2], c2);
                c3 = VFMA(wrow[jj+3], a2[jj+3], c3);
            }
            f2 cc = (c0 + c1) + (c2 + c3);
            ws[OFF_OUT + (b*LQ + q)*NH + tid] = bo[tid] + cc.x + cc.y;
        }
        __syncthreads();
    }
}

// ---------------- gi = xs @ wih.T + bih for both directions ----------------
__global__ __launch_bounds__(384) void k_gi(
        const float* __restrict__ wih_f, const float* __restrict__ bih_f,
        const float* __restrict__ wih_b, const float* __restrict__ bih_b,
        float* __restrict__ ws) {
    int dir = blockIdx.x >> 7;
    int t = blockIdx.x & 127;
    int r = threadIdx.x;
    __shared__ float xr[B*NH];
    for (int i = r; i < B*NH; i += 384) {
        int bb = i >> 7, j = i & 127;
        xr[i] = ws[OFF_OUT + (bb*LQ + t)*NH + j];
    }
    __syncthreads();
    const float* wih = dir ? wih_b : wih_f;
    const float* bih = dir ? bih_b : bih_f;
    const f2* w2 = (const f2*)(wih + r*NH);
    const f2* x0 = (const f2*)(xr + 0*NH);
    const f2* x1 = (const f2*)(xr + 1*NH);
    const f2* x2 = (const f2*)(xr + 2*NH);
    const f2* x3 = (const f2*)(xr + 3*NH);
    f2 a0 = {0.f,0.f}, a1 = {0.f,0.f}, a2 = {0.f,0.f}, a3 = {0.f,0.f};
    #pragma unroll
    for (int c = 0; c < NH/2; ++c) {
        f2 w = w2[c];
        a0 = VFMA(w, x0[c], a0);
        a1 = VFMA(w, x1[c], a1);
        a2 = VFMA(w, x2[c], a2);
        a3 = VFMA(w, x3[c], a3);
    }
    float bb0 = bih[r];
    float* gid = ws + OFF_GI + dir*(LQ*B*G3) + t*(B*G3);
    gid[0*G3 + r] = bb0 + a0.x + a0.y;
    gid[1*G3 + r] = bb0 + a1.x + a1.y;
    gid[2*G3 + r] = bb0 + a2.x + a2.y;
    gid[3*G3 + r] = bb0 + a3.x + a3.y;
}

// ---------------- sequential GRU (V3) ----------------
// grid = 8 blocks (dir,b), 384 threads = 1 gate row per thread.
// __launch_bounds__(384,1) + explicit f2 w[64] (128 VGPRs) -> weights resident,
// no per-step VMEM weight reload (V1's dominant cost). gh LDS exchange as V1.
__global__ __launch_bounds__(384, 1) void k_gru(
        const float* __restrict__ whh_f, const float* __restrict__ bhh_f,
        const float* __restrict__ whh_b, const float* __restrict__ bhh_b,
        float* __restrict__ ws) {
    int dir = blockIdx.x >> 2;
    int b = blockIdx.x & 3;
    int r = threadIdx.x;
    __shared__ float4 hbuf[2][NH/4];
    __shared__ float gh[G3];
    const float* whh = dir ? whh_b : whh_f;
    const float* bhh = dir ? bhh_b : bhh_f;

    f2 w[NH/2];
    #pragma unroll
    for (int c = 0; c < NH/2; ++c) w[c] = ((const f2*)(whh + r*NH))[c];
    float bh = bhh[r];

    if (r < NH) ((float*)hbuf[0])[r] = 0.f;
    float hprev = 0.f;

    const float* gbase = ws + OFF_GI + dir*(LQ*B*G3) + b*G3;
    float* hbase = ws + OFF_H + dir*(LQ*B*NH) + b*NH;

    // gi for step 0 (threads r<NH hold the 3 gate inputs for their row)
    float gir = 0.f, giz = 0.f, gin = 0.f;
    if (r < NH) {
        int tt0 = dir ? (LQ - 1) : 0;
        const float* gp0 = gbase + tt0*(B*G3);
        gir = gp0[r]; giz = gp0[NH + r]; gin = gp0[2*NH + r];
    }
    __syncthreads();

    for (int t = 0; t < LQ; ++t) {
        int tt = dir ? (LQ - 1 - t) : t;
        // prefetch next step's gi (independent of recurrence)
        float ngr = 0.f, ngz = 0.f, ngn = 0.f;
        if (r < NH && t + 1 < LQ) {
            int tn = dir ? (LQ - 2 - t) : (t + 1);
            const float* gp = gbase + tn*(B*G3);
            ngr = gp[r]; ngz = gp[NH + r]; ngn = gp[2*NH + r];
        }
        // row dot against broadcast h (32x ds_read_b128), weights in VGPRs
        const float4* h4 = hbuf[t & 1];
        f2 a0 = {0.f,0.f}, a1 = {0.f,0.f}, a2 = {0.f,0.f}, a3 = {0.f,0.f};
        #pragma unroll
        for (int c = 0; c < NH/4; c += 2) {
            float4 hv0 = h4[c];
            float4 hv1 = h4[c+1];
            f2 l0 = {hv0.x, hv0.y}, l1 = {hv0.z, hv0.w};
            f2 l2 = {hv1.x, hv1.y}, l3 = {hv1.z, hv1.w};
            a0 = VFMA(w[2*c+0], l0, a0);
            a1 = VFMA(w[2*c+1], l1, a1);
            a2 = VFMA(w[2*c+2], l2, a2);
            a3 = VFMA(w[2*c+3], l3, a3);
        }
        f2 aa = (a0 + a1) + (a2 + a3);
        gh[r] = bh + aa.x + aa.y;
        __syncthreads();
        if (r < NH) {
            float rg = fsig(gir + gh[r]);
            float zg = fsig(giz + gh[NH + r]);
            float ng = ftanh2(gin + rg * gh[2*NH + r]);
            float hn = (1.f - zg) * ng + zg * hprev;
            ((float*)hbuf[(t + 1) & 1])[r] = hn;
            hbase[tt*(B*NH) + r] = hn;
            hprev = hn;
        }
        gir = ngr; giz = ngz; gin = ngn;
        __syncthreads();
    }
}

// ---------------- final MLP ----------------
__global__ __launch_bounds__(64) void k_mlp(
        const float* __restrict__ w1, const float* __restrict__ b1,
        const float* __restrict__ w2, const float* __restrict__ b2,
        const float* __restrict__ ws, float* __restrict__ out) {
    int b = blockIdx.x >> 7;
    int q = blockIdx.x & 127;
    int tid = threadIdx.x;
    __shared__ float hh[2*NH];
    __shared__ float hid[64];
    for (int i = tid; i < 2*NH; i += 64) {
        int dir = i >> 7, j = i & 127;
        hh[i] = ws[OFF_H + dir*(LQ*B*NH) + (q*B + b)*NH + j];
    }
    __syncthreads();
    if (tid < 50) {
        const f2* w2v = (const f2*)(w1 + tid*(2*NH));
        const f2* h2v = (const f2*)hh;
        f2 a0 = {0.f,0.f}, a1 = {0.f,0.f}, a2 = {0.f,0.f}, a3 = {0.f,0.f};
        #pragma unroll
        for (int c = 0; c < (2*NH)/2; c += 4) {
            a0 = VFMA(w2v[c+0], h2v[c+0], a0);
            a1 = VFMA(w2v[c+1], h2v[c+1], a1);
            a2 = VFMA(w2v[c+2], h2v[c+2], a2);
            a3 = VFMA(w2v[c+3], h2v[c+3], a3);
        }
        f2 aa = (a0 + a1) + (a2 + a3);
        hid[tid] = fmaxf(b1[tid] + aa.x + aa.y, 0.f);
    }
    __syncthreads();
    if (tid < 40) {
        float acc = b2[tid];
        const float* wr = w2 + tid*50;
        #pragma unroll
        for (int i = 0; i < 50; ++i) acc = fmaf(wr[i], hid[i], acc);
        out[(b*LQ + q)*40 + tid] = acc;
    }
}

extern "C" void kernel_launch(void* const* d_in, const int* in_sizes, int n_in,
                              void* d_out, int out_size, void* d_ws, size_t ws_size,
                              hipStream_t stream) {
    const float* x     = (const float*)d_in[0];
    const float* ts    = (const float*)d_in[1];
    const float* qref  = (const float*)d_in[2];
    const float* wlin  = (const float*)d_in[3];
    const float* blin  = (const float*)d_in[4];
    const float* wper  = (const float*)d_in[5];
    const float* bper  = (const float*)d_in[6];
    const float* wq    = (const float*)d_in[7];
    const float* bq    = (const float*)d_in[8];
    const float* wk    = (const float*)d_in[9];
    const float* bk    = (const float*)d_in[10];
    const float* wo    = (const float*)d_in[11];
    const float* bo    = (const float*)d_in[12];
    const float* wih_f = (const float*)d_in[13];
    const float* whh_f = (const float*)d_in[14];
    const float* bih_f = (const float*)d_in[15];
    const float* bhh_f = (const float*)d_in[16];
    const float* wih_b = (const float*)d_in[17];
    const float* whh_b = (const float*)d_in[18];
    const float* bih_b = (const float*)d_in[19];
    const float* bhh_b = (const float*)d_in[20];
    const float* w1    = (const float*)d_in[21];
    const float* b1    = (const float*)d_in[22];
    const float* w2    = (const float*)d_in[23];
    const float* b2    = (const float*)d_in[24];
    float* ws = (float*)d_ws;
    float* out = (float*)d_out;

    k_emb_proj<<<B*LK + LQ, 128, 0, stream>>>(ts, qref, wlin, blin, wper, bper,
                                              wq, bq, wk, bk, ws);
    k_attn<<<B*(LQ/QTILE), 256, 0, stream>>>(x, wo, bo, ws);
    k_gi<<<2*LQ, 384, 0, stream>>>(wih_f, bih_f, wih_b, bih_b, ws);
    k_gru<<<8, 384, 0, stream>>>(whh_f, bhh_f, whh_b, bhh_b, ws);
    k_mlp<<<B*LQ, 64, 0, stream>>>(w1, b1, w2, b2, ws, out);
}